// Round 16
// baseline (390.205 us; speedup 1.0000x reference)
//
#include <hip/hip_runtime.h>
#include <math.h>

#define BB   2
#define SS   2048
#define HIDD 2048
#define NHH  16
#define HDD  128
#define RDD  64
#define KVCC 512
#define QCC  1536
#define DQK  192
#define MROWS 4096

using bf16x8 = __attribute__((ext_vector_type(8))) short;
using short4v = __attribute__((ext_vector_type(4))) short;
using f32x4  = __attribute__((ext_vector_type(4))) float;
using f32x16 = __attribute__((ext_vector_type(16))) float;

static __device__ __forceinline__ float b2f(short s) {
    unsigned u = ((unsigned)(unsigned short)s) << 16;
    union { unsigned u; float f; } v; v.u = u; return v.f;
}
static __device__ __forceinline__ short f2b(float f) {
    union { float f; unsigned u; } v; v.f = f;
    unsigned r = (v.u + 0x7fffu + ((v.u >> 16) & 1u)) >> 16;
    return (short)r;
}
static __device__ __forceinline__ unsigned cvtpk(float lo, float hi) {
    unsigned r;
    asm("v_cvt_pk_bf16_f32 %0, %1, %2" : "=v"(r) : "v"(lo), "v"(hi));
    return r;
}

#define GLOAD16(gsrc, ldst) \
    __builtin_amdgcn_global_load_lds((const __attribute__((address_space(1))) void*)(gsrc), \
                                     (__attribute__((address_space(3))) void*)(ldst), 16, 0, 0)

// ---------------- fp32 -> bf16 convert ----------------
__global__ void cvt_kernel(const float* __restrict__ in, short* __restrict__ out) {
    int i = (blockIdx.x * blockDim.x + threadIdx.x) * 4;
    float4 v = *(const float4*)(in + i);
    short4v o;
    o[0] = f2b(v.x); o[1] = f2b(v.y); o[2] = f2b(v.z); o[3] = f2b(v.w);
    *(short4v*)(out + i) = o;
}

// ---------------- all 8 weight transposes in ONE launch ----------------
__global__ void wtrans_kernel(
    const float* __restrict__ W0, const float* __restrict__ W1,
    const float* __restrict__ W2, const float* __restrict__ W3,
    const float* __restrict__ W4, const float* __restrict__ W5,
    const float* __restrict__ W6, const float* __restrict__ W7,
    short* __restrict__ D0, short* __restrict__ D1,
    short* __restrict__ D2, short* __restrict__ D3) {
    __shared__ float t[32][33];
    int bid = blockIdx.x;
    const float* W; short* Dst; int K, N, lt;
    if (bid < 4096) {
        if (bid < 1024) { W = W0; Dst = D0;                        K = 2048; N = 512;  lt = bid; }
        else            { W = W1; Dst = D0 + (size_t)512 * 2048;   K = 2048; N = 1536; lt = bid - 1024; }
    } else if (bid < 6656) {
        if (bid < 5120)      { W = W2; Dst = D1;                       K = 512; N = 2048; lt = bid - 4096; }
        else if (bid < 6144) { W = W3; Dst = D1 + (size_t)2048 * 512;  K = 512; N = 2048; lt = bid - 5120; }
        else                 { W = W4; Dst = D1 + (size_t)4096 * 512;  K = 512; N = 1024; lt = bid - 6144; }
    } else if (bid < 11264) {
        if (bid < 9728) { W = W5; Dst = D2;                        K = 1536; N = 2048; lt = bid - 6656; }
        else            { W = W6; Dst = D2 + (size_t)2048 * 1536;  K = 1536; N = 1024; lt = bid - 9728; }
    } else { W = W7; Dst = D3; K = 2048; N = 2048; lt = bid - 11264; }
    int ntx = N >> 5;
    int n0 = (lt % ntx) * 32, k0 = (lt / ntx) * 32;
    int tx = threadIdx.x, ty = threadIdx.y;   // block(32,8)
#pragma unroll
    for (int i = 0; i < 4; i++)
        t[ty + i * 8][tx] = W[(size_t)(k0 + ty + i * 8) * N + n0 + tx];
    __syncthreads();
#pragma unroll
    for (int i = 0; i < 4; i++)
        Dst[(size_t)(n0 + ty + i * 8) * K + k0 + tx] = f2b(t[tx][ty + i * 8]);
}

// ---------------- 128xBN MFMA GEMM, 3-buffer counted-vmcnt pipeline ----------
// BN=128: 16 MFMA/K-step/wave, 2-3 blocks/CU.  BN=64: 8 MFMA, 4 blocks/CU (for
// the N=2048 GEMMs whose 512-block grids under-fill at BN=128).
// ID 0: fp32 out (+b0).  ID 1: [kvc|qc] bf16.
// ID 2: [ku->kbuf | vu->vtb TRANSPOSED (bh,d,s) | kr->kbuf].  ID 3: [qu|qr]->qbuf.
template <int ID, int BN>
__global__ __launch_bounds__(256) void gemm128(
    const short* __restrict__ A, const short* __restrict__ Bt,
    const float* __restrict__ b0, const float* __restrict__ b1, const float* __restrict__ b2,
    void* __restrict__ C0, void* __restrict__ C1,
    int M, int N, int K) {
    constexpr int NF = BN / 32;          // B fragments per wave
    constexpr int LPS = 2 + BN / 64;     // global_load_lds per stage
    __shared__ short Asm[3][4096];       // 3 x [128][32]
    __shared__ short Bsm[3][BN * 32];
    int tid = threadIdx.x, lane = tid & 63, w = tid >> 6;
    int wm = w >> 1, wn = w & 1;
    int m0 = blockIdx.y * 128, n0 = blockIdx.x * BN;
    int fr = lane & 15, fk = (lane >> 4) * 8;
    const short* Ag = A + (size_t)(m0 + (tid >> 2)) * K + (tid & 3) * 8;
    const short* Bg = Bt + (size_t)(n0 + (tid >> 2)) * K + (tid & 3) * 8;
    auto stage = [&](int t, int b) {
        int k0 = t * 32;
        GLOAD16(Ag + k0, &Asm[b][tid * 8]);
        GLOAD16(Ag + k0 + (size_t)64 * K, &Asm[b][2048 + tid * 8]);
        GLOAD16(Bg + k0, &Bsm[b][tid * 8]);
        if constexpr (BN == 128)
            GLOAD16(Bg + k0 + (size_t)64 * K, &Bsm[b][2048 + tid * 8]);
    };
    f32x4 acc[4][NF] = {};
    int NT = K >> 5;
    stage(0, 0);
    stage(1, 1);
    for (int t = 0; t < NT; t++) {
        int cur = t % 3;
        // retire own tile-t loads; tiles t+1/t+2 stay in flight
        if (t + 1 < NT) {
            if constexpr (BN == 128) asm volatile("s_waitcnt vmcnt(4)" ::: "memory");
            else                     asm volatile("s_waitcnt vmcnt(3)" ::: "memory");
        } else {
            asm volatile("s_waitcnt vmcnt(0)" ::: "memory");
        }
        __builtin_amdgcn_s_barrier();   // all waves' tile-t loads visible
        bf16x8 af[4], bfv[NF];
#pragma unroll
        for (int m = 0; m < 4; m++)
            af[m] = *(const bf16x8*)&Asm[cur][(wm * 64 + m * 16 + fr) * 32 + fk];
#pragma unroll
        for (int n = 0; n < NF; n++)
            bfv[n] = *(const bf16x8*)&Bsm[cur][(wn * (BN / 2) + n * 16 + fr) * 32 + fk];
#pragma unroll
        for (int m = 0; m < 4; m++)
#pragma unroll
            for (int n = 0; n < NF; n++)
                acc[m][n] = __builtin_amdgcn_mfma_f32_16x16x32_bf16(af[m], bfv[n], acc[m][n], 0, 0, 0);
        __builtin_amdgcn_s_barrier();   // all waves done reading buf[cur]
        if (t + 2 < NT) stage(t + 2, (t + 2) % 3);   // overwrites buf[(t-1)%3]: safe
    }
#pragma unroll
    for (int m = 0; m < 4; m++)
#pragma unroll
        for (int n = 0; n < NF; n++)
#pragma unroll
            for (int r = 0; r < 4; r++) {
                int row = m0 + wm * 64 + m * 16 + ((lane >> 4) << 2) + r;
                int col = n0 + wn * (BN / 2) + n * 16 + fr;
                float v = acc[m][n][r];
                if constexpr (ID == 0) {
                    ((float*)C0)[(size_t)row * N + col] = v + b0[col];
                } else if constexpr (ID == 1) {
                    if (col < KVCC)
                        ((short*)C0)[(size_t)row * KVCC + col] = f2b(v + b0[col]);
                    else
                        ((short*)C1)[(size_t)row * QCC + (col - KVCC)] = f2b(v + b1[col - KVCC]);
                } else if constexpr (ID == 2) {
                    int b = row >> 11, s = row & (SS - 1);
                    if (col < 2048) {
                        int h = col >> 7, d = col & 127;
                        ((short*)C0)[(((size_t)(b * NHH + h)) * SS + s) * DQK + d] = f2b(v + b0[col]);
                    } else if (col < 4096) {
                        int c = col - 2048; int h = c >> 7, d = c & 127;
                        // direct transposed (bh, d, s) for attention V
                        ((short*)C1)[(((size_t)(b * NHH + h)) * HDD + d) * SS + s] = f2b(v + b1[c]);
                    } else {
                        int c = col - 4096; int h = c >> 6, d = c & 63;
                        ((short*)C0)[(((size_t)(b * NHH + h)) * SS + s) * DQK + HDD + d] = f2b(v + b2[c]);
                    }
                } else {
                    int b = row >> 11, s = row & (SS - 1);
                    if (col < 2048) {
                        int h = col >> 7, d = col & 127;
                        ((short*)C0)[(((size_t)(b * NHH + h)) * SS + s) * DQK + d] = f2b(v + b0[col]);
                    } else {
                        int c = col - 2048; int h = c >> 6, d = c & 63;
                        ((short*)C0)[(((size_t)(b * NHH + h)) * SS + s) * DQK + HDD + d] = f2b(v + b1[c]);
                    }
                }
            }
}

// ---------------- RoPE on [*, *, 128..191] of (B*NH, S, 192), both K and Q ----------------
__global__ void rope_kernel(short* __restrict__ Tk, short* __restrict__ Tq) {
    int idx = blockIdx.x * blockDim.x + threadIdx.x;
    const int HALF = BB * NHH * SS * 32;
    short* T = (idx < HALF) ? Tk : Tq;
    int id = (idx < HALF) ? idx : idx - HALF;
    int i = id & 31;
    int s = (id >> 5) & (SS - 1);
    int bh = id >> 16;
    short* p = T + ((size_t)bh * SS + s) * DQK + HDD;
    float t1 = b2f(p[i]), t2 = b2f(p[i + 32]);
    float inv = exp2f(-(float)i * 0.41524101186092034f);   // 10000^(-i/32)
    float ang = (float)s * inv;
    float sn, cs;
    sincosf(ang, &sn, &cs);
    p[i] = f2b(t1 * cs - t2 * sn);
    p[i + 32] = f2b(t2 * cs + t1 * sn);
}

// ---------------- causal flash attention: 4 waves x 32 q-rows, swapped-QK 32x32 ----------------
// Double-buffered K/V LDS; one barrier per tile; all staging via global_load_lds.
__global__ __launch_bounds__(256, 2) void attn_kernel(
    const short* __restrict__ Q, const short* __restrict__ Kg,
    const short* __restrict__ Vt, short* __restrict__ ctx) {
    __shared__ short Ksm[2][64 * 192];    // 2 x 24KB, swizzled linear
    __shared__ short Vsm[2][128 * 64];    // 2 x 16KB, V^T (d,k), swizzled
    int tid = threadIdx.x, lane = tid & 63, w = tid >> 6;
    int hf = lane >> 5, l31 = lane & 31;
    // complementary-pair mapping (blocks c and c+256 share a CU)
    int bid = blockIdx.x;
    int half = bid >> 8, a = (bid & 255) >> 5;
    int qt = half ? a : 15 - a;
    int bh = bid & 31;
    int bb = bh >> 4, hd = bh & 15;
    int q0 = qt * 128;
    const short* Qp = Q + (size_t)bh * SS * DQK;
    const short* Kp = Kg + (size_t)bh * SS * DQK;
    const char*  Vp = (const char*)(Vt + (size_t)bh * HDD * SS);
    int wr0 = q0 + w * 32;
    int qrow = wr0 + l31;               // this lane's softmax row
    const float scale = 0.07216878364870323f;   // 1/sqrt(192)
    const float L2E = 1.44269504088896f;

    // Q as B-operand fragments: B[k=8*hf+j][col=l31], dims 16s+8hf+j
    bf16x8 qf[12];
#pragma unroll
    for (int s = 0; s < 12; s++)
        qf[s] = *(const bf16x8*)(Qp + (size_t)qrow * DQK + s * 16 + hf * 8);

    f32x16 acc[4] = {};   // O: acc[n] rows=(r&3)+8*(r>>2)+4*hf, d=n*32+l31
    float mrow = -1e30f, lsum = 0.f;
    int nt = 2 * qt + 2;

    auto stageK = [&](int key0, int b) {
#pragma unroll
        for (int pp = 0; pp < 6; pp++) {
            int flat = pp * 4096 + tid * 16;          // byte offset in 64x384B tile
            int row = flat / 384, bir = flat - row * 384;
            const char* src = (const char*)Kp + (size_t)(key0 + row) * 384 + (bir ^ ((row & 7) << 4));
            GLOAD16(src, (char*)Ksm[b] + flat);
        }
    };
    auto stageV = [&](int key0, int b) {
#pragma unroll
        for (int c = 0; c < 4; c++) {
            int flat = c * 4096 + tid * 16;           // byte offset in 128x128B tile
            int d = flat >> 7, bik = flat & 127;
            const char* src = Vp + (size_t)d * (SS * 2) + (size_t)key0 * 2 + (bik ^ ((d & 7) << 4));
            GLOAD16(src, (char*)Vsm[b] + flat);
        }
    };

    stageK(0, 0); stageV(0, 0);
    __syncthreads();   // tile 0 ready

    for (int t0 = 0; t0 < nt; t0++) {
        int key0 = t0 * 64;
        int cur = t0 & 1;
        if (t0 + 1 < nt) { stageK(key0 + 64, cur ^ 1); stageV(key0 + 64, cur ^ 1); }
        bool active = (key0 <= wr0 + 31);
        if (active) {
            // ---- swapped QK^T: D[key][qrow] ----
            f32x16 z = {};
            f32x16 sv0 = z, sv1 = z;
            int xr = (l31 & 7) << 4;
            const char* Kb = (const char*)Ksm[cur];
            __builtin_amdgcn_s_setprio(1);
#pragma unroll
            for (int s = 0; s < 12; s++) {
                bf16x8 k0 = *(const bf16x8*)(Kb + l31 * 384 + ((s * 32 + hf * 16) ^ xr));
                bf16x8 k1 = *(const bf16x8*)(Kb + (32 + l31) * 384 + ((s * 32 + hf * 16) ^ xr));
                sv0 = __builtin_amdgcn_mfma_f32_32x32x16_bf16(k0, qf[s], sv0, 0, 0, 0);
                sv1 = __builtin_amdgcn_mfma_f32_32x32x16_bf16(k1, qf[s], sv1, 0, 0, 0);
            }
            __builtin_amdgcn_s_setprio(0);
            // ---- mask (raw scores; scale folded into exp) ----
            bool domask = (key0 + 63 > wr0);
            float p[32];
#pragma unroll
            for (int t = 0; t < 2; t++)
#pragma unroll
                for (int r = 0; r < 16; r++) {
                    float v = (t ? sv1[r] : sv0[r]);
                    int key = key0 + 32 * t + (r & 3) + 8 * (r >> 2) + 4 * hf;
                    if (domask && key > qrow) v = -1e30f;
                    p[t * 16 + r] = v;
                }
            // ---- tree max (5-deep instead of 31-deep serial chain) ----
            float tm[16];
#pragma unroll
            for (int i = 0; i < 16; i++) tm[i] = fmaxf(p[i], p[i + 16]);
#pragma unroll
            for (int i = 0; i < 8; i++) tm[i] = fmaxf(tm[i], tm[i + 8]);
#pragma unroll
            for (int i = 0; i < 4; i++) tm[i] = fmaxf(tm[i], tm[i + 4]);
            float pmaxs = fmaxf(fmaxf(tm[0], tm[1]), fmaxf(tm[2], tm[3])) * scale;
            // ---- defer-max rescale (common max computed only when needed) ----
            if (__any(pmaxs > mrow + 8.f)) {
                float pc = fmaxf(pmaxs, __shfl_xor(pmaxs, 32, 64));
                float mn = fmaxf(mrow, pc);
                float al = exp2f((mrow - mn) * L2E);
                mrow = mn;
                lsum *= al;
                float arl[16];
#pragma unroll
                for (int r = 0; r < 16; r++)
                    arl[r] = __shfl(al, (r & 3) + 8 * (r >> 2) + 4 * hf, 64);
#pragma unroll
                for (int n = 0; n < 4; n++)
#pragma unroll
                    for (int r = 0; r < 16; r++)
                        acc[n][r] *= arl[r];
            }
            // ---- exp with folded scale: exp2(p*scale*L2E - mrow*L2E) ----
            float sL = scale * L2E, mL = mrow * L2E;
#pragma unroll
            for (int i = 0; i < 32; i++)
                p[i] = exp2f(fmaf(p[i], sL, -mL));
            // ---- tree sum ----
            float ts[16];
#pragma unroll
            for (int i = 0; i < 16; i++) ts[i] = p[i] + p[i + 16];
#pragma unroll
            for (int i = 0; i < 8; i++) ts[i] = ts[i] + ts[i + 8];
#pragma unroll
            for (int i = 0; i < 4; i++) ts[i] = ts[i] + ts[i + 4];
            lsum += (ts[0] + ts[1]) + (ts[2] + ts[3]);
            // ---- pack P to bf16 + exchange halves for ALL slices first ----
            bf16x8 afv[4];
#pragma unroll
            for (int g = 0; g < 4; g++) {   // slice g: keys key0+16g..+15
                int base = (g >> 1) * 16 + (g & 1) * 8;
                unsigned a01 = cvtpk(p[base + 0], p[base + 1]);
                unsigned a23 = cvtpk(p[base + 2], p[base + 3]);
                unsigned b01 = cvtpk(p[base + 4], p[base + 5]);
                unsigned b23 = cvtpk(p[base + 6], p[base + 7]);
                unsigned s0 = hf ? a01 : b01, s1 = hf ? a23 : b23;
                unsigned r0 = (unsigned)__shfl_xor((int)s0, 32, 64);
                unsigned r1 = (unsigned)__shfl_xor((int)s1, 32, 64);
                union { unsigned u[4]; bf16x8 v; } af;
                af.u[0] = hf ? r0 : a01;
                af.u[1] = hf ? r1 : a23;
                af.u[2] = hf ? b01 : r0;
                af.u[3] = hf ? b23 : r1;
                afv[g] = af.v;
            }
            // ---- PV ----
            const char* Vb = (const char*)Vsm[cur];
            __builtin_amdgcn_s_setprio(1);
#pragma unroll
            for (int g = 0; g < 4; g++)
#pragma unroll
                for (int n = 0; n < 4; n++) {
                    int d = n * 32 + l31;
                    bf16x8 vf = *(const bf16x8*)(Vb + d * 128 + ((g * 32 + hf * 16) ^ ((d & 7) << 4)));
                    acc[n] = __builtin_amdgcn_mfma_f32_32x32x16_bf16(afv[g], vf, acc[n], 0, 0, 0);
                }
            __builtin_amdgcn_s_setprio(0);
        }
        // one barrier per tile: syncs all waves' reads of buf[cur] and drains
        // this tile's prefetch (issued a full tile ago -> no stall)
        __syncthreads();
    }
    // ---- epilogue ----
    lsum += __shfl_xor(lsum, 32, 64);
    float rc = 1.0f / lsum;
    float rcl[16];
#pragma unroll
    for (int r = 0; r < 16; r++)
        rcl[r] = __shfl(rc, (r & 3) + 8 * (r >> 2) + 4 * hf, 64);
#pragma unroll
    for (int n = 0; n < 4; n++)
#pragma unroll
        for (int r = 0; r < 16; r++) {
            int row = wr0 + (r & 3) + 8 * (r >> 2) + 4 * hf;
            int d = n * 32 + l31;
            ctx[((size_t)(bb * SS + row)) * (NHH * HDD) + hd * HDD + d] = f2b(acc[n][r] * rcl[r]);
        }
}

extern "C" void kernel_launch(void* const* d_in, const int* in_sizes, int n_in,
                              void* d_out, int out_size, void* d_ws, size_t ws_size,
                              hipStream_t stream) {
    const float* x     = (const float*)d_in[0];
    const float* W_kvd = (const float*)d_in[1];  const float* b_kvd = (const float*)d_in[2];
    const float* W_ku  = (const float*)d_in[3];  const float* b_ku  = (const float*)d_in[4];
    const float* W_vu  = (const float*)d_in[5];  const float* b_vu  = (const float*)d_in[6];
    const float* W_kr  = (const float*)d_in[7];  const float* b_kr  = (const float*)d_in[8];
    const float* W_qd  = (const float*)d_in[9];  const float* b_qd  = (const float*)d_in[10];
    const float* W_qu  = (const float*)d_in[11]; const float* b_qu  = (const float*)d_in[12];
    const float* W_qr  = (const float*)d_in[13]; const float* b_qr  = (const float*)d_in[14];
    const float* W_o   = (const float*)d_in[15]; const float* b_o   = (const float*)d_in[16];
    float* out = (float*)d_out;

    char* p = (char*)d_ws;
    auto alloc = [&](size_t elems) {
        short* r = (short*)p;
        p += ((elems * 2) + 255) & ~(size_t)255;
        return r;
    };
    short* xb   = alloc((size_t)MROWS * HIDD);
    short* kvc  = alloc((size_t)MROWS * KVCC);
    short* qc   = alloc((size_t)MROWS * QCC);
    short* kbuf = alloc((size_t)BB * NHH * SS * DQK);
    short* qbuf = alloc((size_t)BB * NHH * SS * DQK);
    short* vtb  = alloc((size_t)BB * NHH * HDD * SS);
    short* ctx  = alloc((size_t)MROWS * NHH * HDD);
    short* Wt1  = alloc((size_t)2048 * 2048);
    short* Wt2  = alloc((size_t)5120 * 512);
    short* Wt3  = alloc((size_t)3072 * 1536);
    short* Wt4  = alloc((size_t)2048 * 2048);

    cvt_kernel<<<dim3((MROWS * HIDD) / 1024), dim3(256), 0, stream>>>(x, xb);
    dim3 tb(32, 8);
    wtrans_kernel<<<dim3(15360), tb, 0, stream>>>(
        W_kvd, W_qd, W_ku, W_vu, W_kr, W_qu, W_qr, W_o, Wt1, Wt2, Wt3, Wt4);

    gemm128<1, 64><<<dim3(2048 / 64, MROWS / 128), 256, 0, stream>>>(
        xb, Wt1, b_kvd, b_qd, nullptr, kvc, qc, MROWS, 2048, 2048);
    gemm128<2, 128><<<dim3(5120 / 128, MROWS / 128), 256, 0, stream>>>(
        kvc, Wt2, b_ku, b_vu, b_kr, kbuf, vtb, MROWS, 5120, 512);
    gemm128<3, 128><<<dim3(3072 / 128, MROWS / 128), 256, 0, stream>>>(
        qc, Wt3, b_qu, b_qr, nullptr, qbuf, nullptr, MROWS, 3072, 1536);

    rope_kernel<<<dim3((2 * BB * NHH * SS * 32) / 256), dim3(256), 0, stream>>>(kbuf, qbuf);

    attn_kernel<<<dim3(512), 256, 0, stream>>>(qbuf, kbuf, vtb, ctx);

    gemm128<0, 64><<<dim3(2048 / 64, MROWS / 128), 256, 0, stream>>>(
        ctx, Wt4, b_o, nullptr, nullptr, out, nullptr, MROWS, HIDD, NHH * HDD);
}

// Round 17
// 389.205 us; speedup vs baseline: 1.0026x; 1.0026x over previous
//
#include <hip/hip_runtime.h>
#include <math.h>

#define BB   2
#define SS   2048
#define HIDD 2048
#define NHH  16
#define HDD  128
#define RDD  64
#define KVCC 512
#define QCC  1536
#define DQK  192
#define MROWS 4096

using bf16x8 = __attribute__((ext_vector_type(8))) short;
using short4v = __attribute__((ext_vector_type(4))) short;
using f32x4  = __attribute__((ext_vector_type(4))) float;
using f32x16 = __attribute__((ext_vector_type(16))) float;

static __device__ __forceinline__ float b2f(short s) {
    unsigned u = ((unsigned)(unsigned short)s) << 16;
    union { unsigned u; float f; } v; v.u = u; return v.f;
}
static __device__ __forceinline__ short f2b(float f) {
    union { float f; unsigned u; } v; v.f = f;
    unsigned r = (v.u + 0x7fffu + ((v.u >> 16) & 1u)) >> 16;
    return (short)r;
}
static __device__ __forceinline__ unsigned cvtpk(float lo, float hi) {
    unsigned r;
    asm("v_cvt_pk_bf16_f32 %0, %1, %2" : "=v"(r) : "v"(lo), "v"(hi));
    return r;
}

#define GLOAD16(gsrc, ldst) \
    __builtin_amdgcn_global_load_lds((const __attribute__((address_space(1))) void*)(gsrc), \
                                     (__attribute__((address_space(3))) void*)(ldst), 16, 0, 0)

// ---------------- fp32 -> bf16 convert ----------------
__global__ void cvt_kernel(const float* __restrict__ in, short* __restrict__ out) {
    int i = (blockIdx.x * blockDim.x + threadIdx.x) * 4;
    float4 v = *(const float4*)(in + i);
    short4v o;
    o[0] = f2b(v.x); o[1] = f2b(v.y); o[2] = f2b(v.z); o[3] = f2b(v.w);
    *(short4v*)(out + i) = o;
}

// ---------------- all 8 weight transposes in ONE launch ----------------
__global__ void wtrans_kernel(
    const float* __restrict__ W0, const float* __restrict__ W1,
    const float* __restrict__ W2, const float* __restrict__ W3,
    const float* __restrict__ W4, const float* __restrict__ W5,
    const float* __restrict__ W6, const float* __restrict__ W7,
    short* __restrict__ D0, short* __restrict__ D1,
    short* __restrict__ D2, short* __restrict__ D3) {
    __shared__ float t[32][33];
    int bid = blockIdx.x;
    const float* W; short* Dst; int K, N, lt;
    if (bid < 4096) {
        if (bid < 1024) { W = W0; Dst = D0;                        K = 2048; N = 512;  lt = bid; }
        else            { W = W1; Dst = D0 + (size_t)512 * 2048;   K = 2048; N = 1536; lt = bid - 1024; }
    } else if (bid < 6656) {
        if (bid < 5120)      { W = W2; Dst = D1;                       K = 512; N = 2048; lt = bid - 4096; }
        else if (bid < 6144) { W = W3; Dst = D1 + (size_t)2048 * 512;  K = 512; N = 2048; lt = bid - 5120; }
        else                 { W = W4; Dst = D1 + (size_t)4096 * 512;  K = 512; N = 1024; lt = bid - 6144; }
    } else if (bid < 11264) {
        if (bid < 9728) { W = W5; Dst = D2;                        K = 1536; N = 2048; lt = bid - 6656; }
        else            { W = W6; Dst = D2 + (size_t)2048 * 1536;  K = 1536; N = 1024; lt = bid - 9728; }
    } else { W = W7; Dst = D3; K = 2048; N = 2048; lt = bid - 11264; }
    int ntx = N >> 5;
    int n0 = (lt % ntx) * 32, k0 = (lt / ntx) * 32;
    int tx = threadIdx.x, ty = threadIdx.y;   // block(32,8)
#pragma unroll
    for (int i = 0; i < 4; i++)
        t[ty + i * 8][tx] = W[(size_t)(k0 + ty + i * 8) * N + n0 + tx];
    __syncthreads();
#pragma unroll
    for (int i = 0; i < 4; i++)
        Dst[(size_t)(n0 + ty + i * 8) * K + k0 + tx] = f2b(t[tx][ty + i * 8]);
}

// ---------------- 128x128 MFMA GEMM, 3-buffer counted-vmcnt + XCD swizzle ----------
// ID 0: fp32 out (+b0).  ID 1: [kvc|qc] bf16.
template <int ID>
__global__ __launch_bounds__(256) void gemm128(
    const short* __restrict__ A, const short* __restrict__ Bt,
    const float* __restrict__ b0, const float* __restrict__ b1,
    void* __restrict__ C0, void* __restrict__ C1,
    int M, int N, int K) {
    __shared__ short Asm[3][4096];   // 3 x [128][32]
    __shared__ short Bsm[3][4096];
    int tid = threadIdx.x, lane = tid & 63, w = tid >> 6;
    int wm = w >> 1, wn = w & 1;
    // XCD-aware swizzle (grid % 8 == 0): each XCD gets a contiguous chunk
    int nbx = N >> 7;
    int cpx = gridDim.x >> 3;
    int swz = ((int)blockIdx.x & 7) * cpx + ((int)blockIdx.x >> 3);
    int m0 = (swz / nbx) * 128, n0 = (swz % nbx) * 128;
    int fr = lane & 15, fk = (lane >> 4) * 8;
    const short* Ag = A + (size_t)(m0 + (tid >> 2)) * K + (tid & 3) * 8;
    const short* Bg = Bt + (size_t)(n0 + (tid >> 2)) * K + (tid & 3) * 8;
    auto stage = [&](int t, int b) {
        int k0 = t * 32;
        GLOAD16(Ag + k0, &Asm[b][tid * 8]);
        GLOAD16(Ag + k0 + (size_t)64 * K, &Asm[b][2048 + tid * 8]);
        GLOAD16(Bg + k0, &Bsm[b][tid * 8]);
        GLOAD16(Bg + k0 + (size_t)64 * K, &Bsm[b][2048 + tid * 8]);
    };
    f32x4 acc[4][4] = {};
    int NT = K >> 5;
    stage(0, 0);
    stage(1, 1);
    for (int t = 0; t < NT; t++) {
        int cur = t % 3;
        if (t + 1 < NT) asm volatile("s_waitcnt vmcnt(4)" ::: "memory");
        else            asm volatile("s_waitcnt vmcnt(0)" ::: "memory");
        __builtin_amdgcn_s_barrier();
        bf16x8 af[4], bfv[4];
#pragma unroll
        for (int m = 0; m < 4; m++)
            af[m] = *(const bf16x8*)&Asm[cur][(wm * 64 + m * 16 + fr) * 32 + fk];
#pragma unroll
        for (int n = 0; n < 4; n++)
            bfv[n] = *(const bf16x8*)&Bsm[cur][(wn * 64 + n * 16 + fr) * 32 + fk];
#pragma unroll
        for (int m = 0; m < 4; m++)
#pragma unroll
            for (int n = 0; n < 4; n++)
                acc[m][n] = __builtin_amdgcn_mfma_f32_16x16x32_bf16(af[m], bfv[n], acc[m][n], 0, 0, 0);
        __builtin_amdgcn_s_barrier();
        if (t + 2 < NT) stage(t + 2, (t + 2) % 3);
    }
#pragma unroll
    for (int m = 0; m < 4; m++)
#pragma unroll
        for (int n = 0; n < 4; n++)
#pragma unroll
            for (int r = 0; r < 4; r++) {
                int row = m0 + wm * 64 + m * 16 + ((lane >> 4) << 2) + r;
                int col = n0 + wn * 64 + n * 16 + fr;
                float v = acc[m][n][r];
                if constexpr (ID == 0) {
                    ((float*)C0)[(size_t)row * N + col] = v + b0[col];
                } else {
                    if (col < KVCC)
                        ((short*)C0)[(size_t)row * KVCC + col] = f2b(v + b0[col]);
                    else
                        ((short*)C1)[(size_t)row * QCC + (col - KVCC)] = f2b(v + b1[col - KVCC]);
                }
            }
}

// ---------------- merged gemm2+gemm3, work-balanced 3:5 stripe + XCD swizzle ----------
// gemm3: qc @ Wt3 -> [qu|qr] -> qbuf (768 blocks, K=1536)
// gemm2: kvc @ Wt2 -> [ku->kbuf | vu->vtb(d,s) | kr->kbuf] (1280 blocks, K=512)
__global__ __launch_bounds__(256) void gemm23_kernel(
    const short* __restrict__ kvc, const short* __restrict__ qc,
    const short* __restrict__ Wt2, const short* __restrict__ Wt3,
    const float* __restrict__ b_ku, const float* __restrict__ b_vu, const float* __restrict__ b_kr,
    const float* __restrict__ b_qu, const float* __restrict__ b_qr,
    short* __restrict__ kbuf, short* __restrict__ qbuf, short* __restrict__ vtb) {
    __shared__ short Asm[3][4096];
    __shared__ short Bsm[3][4096];
    int tid = threadIdx.x, lane = tid & 63, w = tid >> 6;
    int wm = w >> 1, wn = w & 1;
    int cpx = gridDim.x >> 3;                       // 256
    int swz = ((int)blockIdx.x & 7) * cpx + ((int)blockIdx.x >> 3);
    int g = swz >> 3, rm = swz & 7;
    bool is3 = rm < 3;                              // 3:5 stripe -> 768 / 1280
    const short *A, *Bt; int K, nbx, lid;
    if (is3) { A = qc;  Bt = Wt3; K = 1536; nbx = 3072 / 128; lid = g * 3 + rm; }
    else     { A = kvc; Bt = Wt2; K = 512;  nbx = 5120 / 128; lid = g * 5 + (rm - 3); }
    int m0 = (lid / nbx) * 128, n0 = (lid % nbx) * 128;
    int fr = lane & 15, fk = (lane >> 4) * 8;
    const short* Ag = A + (size_t)(m0 + (tid >> 2)) * K + (tid & 3) * 8;
    const short* Bg = Bt + (size_t)(n0 + (tid >> 2)) * K + (tid & 3) * 8;
    auto stage = [&](int t, int b) {
        int k0 = t * 32;
        GLOAD16(Ag + k0, &Asm[b][tid * 8]);
        GLOAD16(Ag + k0 + (size_t)64 * K, &Asm[b][2048 + tid * 8]);
        GLOAD16(Bg + k0, &Bsm[b][tid * 8]);
        GLOAD16(Bg + k0 + (size_t)64 * K, &Bsm[b][2048 + tid * 8]);
    };
    f32x4 acc[4][4] = {};
    int NT = K >> 5;
    stage(0, 0);
    stage(1, 1);
    for (int t = 0; t < NT; t++) {
        int cur = t % 3;
        if (t + 1 < NT) asm volatile("s_waitcnt vmcnt(4)" ::: "memory");
        else            asm volatile("s_waitcnt vmcnt(0)" ::: "memory");
        __builtin_amdgcn_s_barrier();
        bf16x8 af[4], bfv[4];
#pragma unroll
        for (int m = 0; m < 4; m++)
            af[m] = *(const bf16x8*)&Asm[cur][(wm * 64 + m * 16 + fr) * 32 + fk];
#pragma unroll
        for (int n = 0; n < 4; n++)
            bfv[n] = *(const bf16x8*)&Bsm[cur][(wn * 64 + n * 16 + fr) * 32 + fk];
#pragma unroll
        for (int m = 0; m < 4; m++)
#pragma unroll
            for (int n = 0; n < 4; n++)
                acc[m][n] = __builtin_amdgcn_mfma_f32_16x16x32_bf16(af[m], bfv[n], acc[m][n], 0, 0, 0);
        __builtin_amdgcn_s_barrier();
        if (t + 2 < NT) stage(t + 2, (t + 2) % 3);
    }
#pragma unroll
    for (int m = 0; m < 4; m++)
#pragma unroll
        for (int n = 0; n < 4; n++)
#pragma unroll
            for (int r = 0; r < 4; r++) {
                int row = m0 + wm * 64 + m * 16 + ((lane >> 4) << 2) + r;
                int col = n0 + wn * 64 + n * 16 + fr;
                float v = acc[m][n][r];
                int b = row >> 11, s = row & (SS - 1);
                if (is3) {
                    if (col < 2048) {
                        int h = col >> 7, d = col & 127;
                        qbuf[(((size_t)(b * NHH + h)) * SS + s) * DQK + d] = f2b(v + b_qu[col]);
                    } else {
                        int c = col - 2048; int h = c >> 6, d = c & 63;
                        qbuf[(((size_t)(b * NHH + h)) * SS + s) * DQK + HDD + d] = f2b(v + b_qr[c]);
                    }
                } else {
                    if (col < 2048) {
                        int h = col >> 7, d = col & 127;
                        kbuf[(((size_t)(b * NHH + h)) * SS + s) * DQK + d] = f2b(v + b_ku[col]);
                    } else if (col < 4096) {
                        int c = col - 2048; int h = c >> 7, d = c & 127;
                        vtb[(((size_t)(b * NHH + h)) * HDD + d) * SS + s] = f2b(v + b_vu[c]);
                    } else {
                        int c = col - 4096; int h = c >> 6, d = c & 63;
                        kbuf[(((size_t)(b * NHH + h)) * SS + s) * DQK + HDD + d] = f2b(v + b_kr[c]);
                    }
                }
            }
}

// ---------------- RoPE on [*, *, 128..191] of (B*NH, S, 192), both K and Q ----------------
__global__ void rope_kernel(short* __restrict__ Tk, short* __restrict__ Tq) {
    int idx = blockIdx.x * blockDim.x + threadIdx.x;
    const int HALF = BB * NHH * SS * 32;
    short* T = (idx < HALF) ? Tk : Tq;
    int id = (idx < HALF) ? idx : idx - HALF;
    int i = id & 31;
    int s = (id >> 5) & (SS - 1);
    int bh = id >> 16;
    short* p = T + ((size_t)bh * SS + s) * DQK + HDD;
    float t1 = b2f(p[i]), t2 = b2f(p[i + 32]);
    float inv = exp2f(-(float)i * 0.41524101186092034f);   // 10000^(-i/32)
    float ang = (float)s * inv;
    float sn, cs;
    sincosf(ang, &sn, &cs);
    p[i] = f2b(t1 * cs - t2 * sn);
    p[i + 32] = f2b(t2 * cs + t1 * sn);
}

// ---------------- causal flash attention: 4 waves x 32 q-rows, swapped-QK 32x32 ----------------
// Double-buffered K/V LDS; one barrier per tile; all staging via global_load_lds.
__global__ __launch_bounds__(256, 2) void attn_kernel(
    const short* __restrict__ Q, const short* __restrict__ Kg,
    const short* __restrict__ Vt, short* __restrict__ ctx) {
    __shared__ short Ksm[2][64 * 192];    // 2 x 24KB, swizzled linear
    __shared__ short Vsm[2][128 * 64];    // 2 x 16KB, V^T (d,k), swizzled
    int tid = threadIdx.x, lane = tid & 63, w = tid >> 6;
    int hf = lane >> 5, l31 = lane & 31;
    // complementary-pair mapping (blocks c and c+256 share a CU)
    int bid = blockIdx.x;
    int half = bid >> 8, a = (bid & 255) >> 5;
    int qt = half ? a : 15 - a;
    int bh = bid & 31;
    int bb = bh >> 4, hd = bh & 15;
    int q0 = qt * 128;
    const short* Qp = Q + (size_t)bh * SS * DQK;
    const short* Kp = Kg + (size_t)bh * SS * DQK;
    const char*  Vp = (const char*)(Vt + (size_t)bh * HDD * SS);
    int wr0 = q0 + w * 32;
    int qrow = wr0 + l31;               // this lane's softmax row
    const float scale = 0.07216878364870323f;   // 1/sqrt(192)
    const float L2E = 1.44269504088896f;

    // Q as B-operand fragments: B[k=8*hf+j][col=l31], dims 16s+8hf+j
    bf16x8 qf[12];
#pragma unroll
    for (int s = 0; s < 12; s++)
        qf[s] = *(const bf16x8*)(Qp + (size_t)qrow * DQK + s * 16 + hf * 8);

    f32x16 acc[4] = {};   // O: acc[n] rows=(r&3)+8*(r>>2)+4*hf, d=n*32+l31
    float mrow = -1e30f, lsum = 0.f;
    int nt = 2 * qt + 2;

    auto stageK = [&](int key0, int b) {
#pragma unroll
        for (int pp = 0; pp < 6; pp++) {
            int flat = pp * 4096 + tid * 16;          // byte offset in 64x384B tile
            int row = flat / 384, bir = flat - row * 384;
            const char* src = (const char*)Kp + (size_t)(key0 + row) * 384 + (bir ^ ((row & 7) << 4));
            GLOAD16(src, (char*)Ksm[b] + flat);
        }
    };
    auto stageV = [&](int key0, int b) {
#pragma unroll
        for (int c = 0; c < 4; c++) {
            int flat = c * 4096 + tid * 16;           // byte offset in 128x128B tile
            int d = flat >> 7, bik = flat & 127;
            const char* src = Vp + (size_t)d * (SS * 2) + (size_t)key0 * 2 + (bik ^ ((d & 7) << 4));
            GLOAD16(src, (char*)Vsm[b] + flat);
        }
    };

    stageK(0, 0); stageV(0, 0);
    __syncthreads();   // tile 0 ready

    for (int t0 = 0; t0 < nt; t0++) {
        int key0 = t0 * 64;
        int cur = t0 & 1;
        if (t0 + 1 < nt) { stageK(key0 + 64, cur ^ 1); stageV(key0 + 64, cur ^ 1); }
        bool active = (key0 <= wr0 + 31);
        if (active) {
            // ---- swapped QK^T: D[key][qrow] ----
            f32x16 z = {};
            f32x16 sv0 = z, sv1 = z;
            int xr = (l31 & 7) << 4;
            const char* Kb = (const char*)Ksm[cur];
            __builtin_amdgcn_s_setprio(1);
#pragma unroll
            for (int s = 0; s < 12; s++) {
                bf16x8 k0 = *(const bf16x8*)(Kb + l31 * 384 + ((s * 32 + hf * 16) ^ xr));
                bf16x8 k1 = *(const bf16x8*)(Kb + (32 + l31) * 384 + ((s * 32 + hf * 16) ^ xr));
                sv0 = __builtin_amdgcn_mfma_f32_32x32x16_bf16(k0, qf[s], sv0, 0, 0, 0);
                sv1 = __builtin_amdgcn_mfma_f32_32x32x16_bf16(k1, qf[s], sv1, 0, 0, 0);
            }
            __builtin_amdgcn_s_setprio(0);
            // ---- mask (raw scores; scale folded into exp) ----
            bool domask = (key0 + 63 > wr0);
            float p[32];
#pragma unroll
            for (int t = 0; t < 2; t++)
#pragma unroll
                for (int r = 0; r < 16; r++) {
                    float v = (t ? sv1[r] : sv0[r]);
                    int key = key0 + 32 * t + (r & 3) + 8 * (r >> 2) + 4 * hf;
                    if (domask && key > qrow) v = -1e30f;
                    p[t * 16 + r] = v;
                }
            // ---- tree max (5-deep instead of 31-deep serial chain) ----
            float tm[16];
#pragma unroll
            for (int i = 0; i < 16; i++) tm[i] = fmaxf(p[i], p[i + 16]);
#pragma unroll
            for (int i = 0; i < 8; i++) tm[i] = fmaxf(tm[i], tm[i + 8]);
#pragma unroll
            for (int i = 0; i < 4; i++) tm[i] = fmaxf(tm[i], tm[i + 4]);
            float pmaxs = fmaxf(fmaxf(tm[0], tm[1]), fmaxf(tm[2], tm[3])) * scale;
            // ---- defer-max rescale (common max computed only when needed) ----
            if (__any(pmaxs > mrow + 8.f)) {
                float pc = fmaxf(pmaxs, __shfl_xor(pmaxs, 32, 64));
                float mn = fmaxf(mrow, pc);
                float al = exp2f((mrow - mn) * L2E);
                mrow = mn;
                lsum *= al;
                float arl[16];
#pragma unroll
                for (int r = 0; r < 16; r++)
                    arl[r] = __shfl(al, (r & 3) + 8 * (r >> 2) + 4 * hf, 64);
#pragma unroll
                for (int n = 0; n < 4; n++)
#pragma unroll
                    for (int r = 0; r < 16; r++)
                        acc[n][r] *= arl[r];
            }
            // ---- exp with folded scale: exp2(p*scale*L2E - mrow*L2E) ----
            float sL = scale * L2E, mL = mrow * L2E;
#pragma unroll
            for (int i = 0; i < 32; i++)
                p[i] = exp2f(fmaf(p[i], sL, -mL));
            // ---- tree sum ----
            float ts[16];
#pragma unroll
            for (int i = 0; i < 16; i++) ts[i] = p[i] + p[i + 16];
#pragma unroll
            for (int i = 0; i < 8; i++) ts[i] = ts[i] + ts[i + 8];
#pragma unroll
            for (int i = 0; i < 4; i++) ts[i] = ts[i] + ts[i + 4];
            lsum += (ts[0] + ts[1]) + (ts[2] + ts[3]);
            // ---- pack P to bf16 + exchange halves for ALL slices first ----
            bf16x8 afv[4];
#pragma unroll
            for (int g = 0; g < 4; g++) {   // slice g: keys key0+16g..+15
                int base = (g >> 1) * 16 + (g & 1) * 8;
                unsigned a01 = cvtpk(p[base + 0], p[base + 1]);
                unsigned a23 = cvtpk(p[base + 2], p[base + 3]);
                unsigned b01 = cvtpk(p[base + 4], p[base + 5]);
                unsigned b23 = cvtpk(p[base + 6], p[base + 7]);
                unsigned s0 = hf ? a01 : b01, s1 = hf ? a23 : b23;
                unsigned r0 = (unsigned)__shfl_xor((int)s0, 32, 64);
                unsigned r1 = (unsigned)__shfl_xor((int)s1, 32, 64);
                union { unsigned u[4]; bf16x8 v; } af;
                af.u[0] = hf ? r0 : a01;
                af.u[1] = hf ? r1 : a23;
                af.u[2] = hf ? b01 : r0;
                af.u[3] = hf ? b23 : r1;
                afv[g] = af.v;
            }
            // ---- PV ----
            const char* Vb = (const char*)Vsm[cur];
            __builtin_amdgcn_s_setprio(1);
#pragma unroll
            for (int g = 0; g < 4; g++)
#pragma unroll
                for (int n = 0; n < 4; n++) {
                    int d = n * 32 + l31;
                    bf16x8 vf = *(const bf16x8*)(Vb + d * 128 + ((g * 32 + hf * 16) ^ ((d & 7) << 4)));
                    acc[n] = __builtin_amdgcn_mfma_f32_32x32x16_bf16(afv[g], vf, acc[n], 0, 0, 0);
                }
            __builtin_amdgcn_s_setprio(0);
        }
        // one barrier per tile: syncs all waves' reads of buf[cur] and drains
        // this tile's prefetch (issued a full tile ago -> no stall)
        __syncthreads();
    }
    // ---- epilogue ----
    lsum += __shfl_xor(lsum, 32, 64);
    float rc = 1.0f / lsum;
    float rcl[16];
#pragma unroll
    for (int r = 0; r < 16; r++)
        rcl[r] = __shfl(rc, (r & 3) + 8 * (r >> 2) + 4 * hf, 64);
#pragma unroll
    for (int n = 0; n < 4; n++)
#pragma unroll
        for (int r = 0; r < 16; r++) {
            int row = wr0 + (r & 3) + 8 * (r >> 2) + 4 * hf;
            int d = n * 32 + l31;
            ctx[((size_t)(bb * SS + row)) * (NHH * HDD) + hd * HDD + d] = f2b(acc[n][r] * rcl[r]);
        }
}

extern "C" void kernel_launch(void* const* d_in, const int* in_sizes, int n_in,
                              void* d_out, int out_size, void* d_ws, size_t ws_size,
                              hipStream_t stream) {
    const float* x     = (const float*)d_in[0];
    const float* W_kvd = (const float*)d_in[1];  const float* b_kvd = (const float*)d_in[2];
    const float* W_ku  = (const float*)d_in[3];  const float* b_ku  = (const float*)d_in[4];
    const float* W_vu  = (const float*)d_in[5];  const float* b_vu  = (const float*)d_in[6];
    const float* W_kr  = (const float*)d_in[7];  const float* b_kr  = (const float*)d_in[8];
    const float* W_qd  = (const float*)d_in[9];  const float* b_qd  = (const float*)d_in[10];
    const float* W_qu  = (const float*)d_in[11]; const float* b_qu  = (const float*)d_in[12];
    const float* W_qr  = (const float*)d_in[13]; const float* b_qr  = (const float*)d_in[14];
    const float* W_o   = (const float*)d_in[15]; const float* b_o   = (const float*)d_in[16];
    float* out = (float*)d_out;

    char* p = (char*)d_ws;
    auto alloc = [&](size_t elems) {
        short* r = (short*)p;
        p += ((elems * 2) + 255) & ~(size_t)255;
        return r;
    };
    short* xb   = alloc((size_t)MROWS * HIDD);
    short* kvc  = alloc((size_t)MROWS * KVCC);
    short* qc   = alloc((size_t)MROWS * QCC);
    short* kbuf = alloc((size_t)BB * NHH * SS * DQK);
    short* qbuf = alloc((size_t)BB * NHH * SS * DQK);
    short* vtb  = alloc((size_t)BB * NHH * HDD * SS);
    short* ctx  = alloc((size_t)MROWS * NHH * HDD);
    short* Wt1  = alloc((size_t)2048 * 2048);
    short* Wt2  = alloc((size_t)5120 * 512);
    short* Wt3  = alloc((size_t)3072 * 1536);
    short* Wt4  = alloc((size_t)2048 * 2048);

    cvt_kernel<<<dim3((MROWS * HIDD) / 1024), dim3(256), 0, stream>>>(x, xb);
    dim3 tb(32, 8);
    wtrans_kernel<<<dim3(15360), tb, 0, stream>>>(
        W_kvd, W_qd, W_ku, W_vu, W_kr, W_qu, W_qr, W_o, Wt1, Wt2, Wt3, Wt4);

    gemm128<1><<<dim3(512), 256, 0, stream>>>(
        xb, Wt1, b_kvd, b_qd, kvc, qc, MROWS, 2048, 2048);
    gemm23_kernel<<<dim3(2048), 256, 0, stream>>>(
        kvc, qc, Wt2, Wt3, b_ku, b_vu, b_kr, b_qu, b_qr, kbuf, qbuf, vtb);

    rope_kernel<<<dim3((2 * BB * NHH * SS * 32) / 256), dim3(256), 0, stream>>>(kbuf, qbuf);

    attn_kernel<<<dim3(512), 256, 0, stream>>>(qbuf, kbuf, vtb, ctx);

    gemm128<0><<<dim3(512), 256, 0, stream>>>(
        ctx, Wt4, b_o, nullptr, out, nullptr, MROWS, HIDD, NHH * HDD);
}

// Round 18
// 383.859 us; speedup vs baseline: 1.0165x; 1.0139x over previous
//
#include <hip/hip_runtime.h>
#include <math.h>

#define BB   2
#define SS   2048
#define HIDD 2048
#define NHH  16
#define HDD  128
#define RDD  64
#define KVCC 512
#define QCC  1536
#define DQK  192
#define MROWS 4096

using bf16x8 = __attribute__((ext_vector_type(8))) short;
using short4v = __attribute__((ext_vector_type(4))) short;
using f32x4  = __attribute__((ext_vector_type(4))) float;
using f32x16 = __attribute__((ext_vector_type(16))) float;

static __device__ __forceinline__ float b2f(short s) {
    unsigned u = ((unsigned)(unsigned short)s) << 16;
    union { unsigned u; float f; } v; v.u = u; return v.f;
}
static __device__ __forceinline__ short f2b(float f) {
    union { float f; unsigned u; } v; v.f = f;
    unsigned r = (v.u + 0x7fffu + ((v.u >> 16) & 1u)) >> 16;
    return (short)r;
}
static __device__ __forceinline__ unsigned cvtpk(float lo, float hi) {
    unsigned r;
    asm("v_cvt_pk_bf16_f32 %0, %1, %2" : "=v"(r) : "v"(lo), "v"(hi));
    return r;
}

#define GLOAD16(gsrc, ldst) \
    __builtin_amdgcn_global_load_lds((const __attribute__((address_space(1))) void*)(gsrc), \
                                     (__attribute__((address_space(3))) void*)(ldst), 16, 0, 0)

// ---------------- fp32 -> bf16 convert ----------------
__global__ void cvt_kernel(const float* __restrict__ in, short* __restrict__ out) {
    int i = (blockIdx.x * blockDim.x + threadIdx.x) * 4;
    float4 v = *(const float4*)(in + i);
    short4v o;
    o[0] = f2b(v.x); o[1] = f2b(v.y); o[2] = f2b(v.z); o[3] = f2b(v.w);
    *(short4v*)(out + i) = o;
}

// ---------------- all 8 weight transposes in ONE launch ----------------
__global__ void wtrans_kernel(
    const float* __restrict__ W0, const float* __restrict__ W1,
    const float* __restrict__ W2, const float* __restrict__ W3,
    const float* __restrict__ W4, const float* __restrict__ W5,
    const float* __restrict__ W6, const float* __restrict__ W7,
    short* __restrict__ D0, short* __restrict__ D1,
    short* __restrict__ D2, short* __restrict__ D3) {
    __shared__ float t[32][33];
    int bid = blockIdx.x;
    const float* W; short* Dst; int K, N, lt;
    if (bid < 4096) {
        if (bid < 1024) { W = W0; Dst = D0;                        K = 2048; N = 512;  lt = bid; }
        else            { W = W1; Dst = D0 + (size_t)512 * 2048;   K = 2048; N = 1536; lt = bid - 1024; }
    } else if (bid < 6656) {
        if (bid < 5120)      { W = W2; Dst = D1;                       K = 512; N = 2048; lt = bid - 4096; }
        else if (bid < 6144) { W = W3; Dst = D1 + (size_t)2048 * 512;  K = 512; N = 2048; lt = bid - 5120; }
        else                 { W = W4; Dst = D1 + (size_t)4096 * 512;  K = 512; N = 1024; lt = bid - 6144; }
    } else if (bid < 11264) {
        if (bid < 9728) { W = W5; Dst = D2;                        K = 1536; N = 2048; lt = bid - 6656; }
        else            { W = W6; Dst = D2 + (size_t)2048 * 1536;  K = 1536; N = 1024; lt = bid - 9728; }
    } else { W = W7; Dst = D3; K = 2048; N = 2048; lt = bid - 11264; }
    int ntx = N >> 5;
    int n0 = (lt % ntx) * 32, k0 = (lt / ntx) * 32;
    int tx = threadIdx.x, ty = threadIdx.y;   // block(32,8)
#pragma unroll
    for (int i = 0; i < 4; i++)
        t[ty + i * 8][tx] = W[(size_t)(k0 + ty + i * 8) * N + n0 + tx];
    __syncthreads();
#pragma unroll
    for (int i = 0; i < 4; i++)
        Dst[(size_t)(n0 + ty + i * 8) * K + k0 + tx] = f2b(t[tx][ty + i * 8]);
}

// ---------------- 128x128 MFMA GEMM, 3-buffer counted-vmcnt + XCD swizzle ----------
// ID 0: fp32 out (+b0).  ID 1: [kvc|qc] bf16.
// ID 2: [ku->kbuf | vu->vtb TRANSPOSED (bh,d,s) | kr->kbuf].  ID 3: [qu|qr]->qbuf.
template <int ID>
__global__ __launch_bounds__(256) void gemm128(
    const short* __restrict__ A, const short* __restrict__ Bt,
    const float* __restrict__ b0, const float* __restrict__ b1, const float* __restrict__ b2,
    void* __restrict__ C0, void* __restrict__ C1,
    int M, int N, int K) {
    __shared__ short Asm[3][4096];   // 3 x [128][32]
    __shared__ short Bsm[3][4096];
    int tid = threadIdx.x, lane = tid & 63, w = tid >> 6;
    int wm = w >> 1, wn = w & 1;
    // XCD-aware swizzle (grid % 8 == 0): each XCD gets a contiguous chunk
    int nbx = N >> 7;
    int cpx = gridDim.x >> 3;
    int swz = ((int)blockIdx.x & 7) * cpx + ((int)blockIdx.x >> 3);
    int m0 = (swz / nbx) * 128, n0 = (swz % nbx) * 128;
    int fr = lane & 15, fk = (lane >> 4) * 8;
    const short* Ag = A + (size_t)(m0 + (tid >> 2)) * K + (tid & 3) * 8;
    const short* Bg = Bt + (size_t)(n0 + (tid >> 2)) * K + (tid & 3) * 8;
    auto stage = [&](int t, int b) {
        int k0 = t * 32;
        GLOAD16(Ag + k0, &Asm[b][tid * 8]);
        GLOAD16(Ag + k0 + (size_t)64 * K, &Asm[b][2048 + tid * 8]);
        GLOAD16(Bg + k0, &Bsm[b][tid * 8]);
        GLOAD16(Bg + k0 + (size_t)64 * K, &Bsm[b][2048 + tid * 8]);
    };
    f32x4 acc[4][4] = {};
    int NT = K >> 5;
    stage(0, 0);
    stage(1, 1);
    for (int t = 0; t < NT; t++) {
        int cur = t % 3;
        if (t + 1 < NT) asm volatile("s_waitcnt vmcnt(4)" ::: "memory");
        else            asm volatile("s_waitcnt vmcnt(0)" ::: "memory");
        __builtin_amdgcn_s_barrier();
        bf16x8 af[4], bfv[4];
#pragma unroll
        for (int m = 0; m < 4; m++)
            af[m] = *(const bf16x8*)&Asm[cur][(wm * 64 + m * 16 + fr) * 32 + fk];
#pragma unroll
        for (int n = 0; n < 4; n++)
            bfv[n] = *(const bf16x8*)&Bsm[cur][(wn * 64 + n * 16 + fr) * 32 + fk];
#pragma unroll
        for (int m = 0; m < 4; m++)
#pragma unroll
            for (int n = 0; n < 4; n++)
                acc[m][n] = __builtin_amdgcn_mfma_f32_16x16x32_bf16(af[m], bfv[n], acc[m][n], 0, 0, 0);
        __builtin_amdgcn_s_barrier();
        if (t + 2 < NT) stage(t + 2, (t + 2) % 3);
    }
#pragma unroll
    for (int m = 0; m < 4; m++)
#pragma unroll
        for (int n = 0; n < 4; n++)
#pragma unroll
            for (int r = 0; r < 4; r++) {
                int row = m0 + wm * 64 + m * 16 + ((lane >> 4) << 2) + r;
                int col = n0 + wn * 64 + n * 16 + fr;
                float v = acc[m][n][r];
                if constexpr (ID == 0) {
                    ((float*)C0)[(size_t)row * N + col] = v + b0[col];
                } else if constexpr (ID == 1) {
                    if (col < KVCC)
                        ((short*)C0)[(size_t)row * KVCC + col] = f2b(v + b0[col]);
                    else
                        ((short*)C1)[(size_t)row * QCC + (col - KVCC)] = f2b(v + b1[col - KVCC]);
                } else if constexpr (ID == 2) {
                    int b = row >> 11, s = row & (SS - 1);
                    if (col < 2048) {
                        int h = col >> 7, d = col & 127;
                        ((short*)C0)[(((size_t)(b * NHH + h)) * SS + s) * DQK + d] = f2b(v + b0[col]);
                    } else if (col < 4096) {
                        int c = col - 2048; int h = c >> 7, d = c & 127;
                        // direct transposed (bh, d, s) for attention V
                        ((short*)C1)[(((size_t)(b * NHH + h)) * HDD + d) * SS + s] = f2b(v + b1[c]);
                    } else {
                        int c = col - 4096; int h = c >> 6, d = c & 63;
                        ((short*)C0)[(((size_t)(b * NHH + h)) * SS + s) * DQK + HDD + d] = f2b(v + b2[c]);
                    }
                } else {
                    int b = row >> 11, s = row & (SS - 1);
                    if (col < 2048) {
                        int h = col >> 7, d = col & 127;
                        ((short*)C0)[(((size_t)(b * NHH + h)) * SS + s) * DQK + d] = f2b(v + b0[col]);
                    } else {
                        int c = col - 2048; int h = c >> 6, d = c & 63;
                        ((short*)C0)[(((size_t)(b * NHH + h)) * SS + s) * DQK + HDD + d] = f2b(v + b1[c]);
                    }
                }
            }
}

// ---------------- RoPE on [*, *, 128..191] of (B*NH, S, 192), both K and Q ----------------
__global__ void rope_kernel(short* __restrict__ Tk, short* __restrict__ Tq) {
    int idx = blockIdx.x * blockDim.x + threadIdx.x;
    const int HALF = BB * NHH * SS * 32;
    short* T = (idx < HALF) ? Tk : Tq;
    int id = (idx < HALF) ? idx : idx - HALF;
    int i = id & 31;
    int s = (id >> 5) & (SS - 1);
    int bh = id >> 16;
    short* p = T + ((size_t)bh * SS + s) * DQK + HDD;
    float t1 = b2f(p[i]), t2 = b2f(p[i + 32]);
    float inv = exp2f(-(float)i * 0.41524101186092034f);   // 10000^(-i/32)
    float ang = (float)s * inv;
    float sn, cs;
    sincosf(ang, &sn, &cs);
    p[i] = f2b(t1 * cs - t2 * sn);
    p[i + 32] = f2b(t2 * cs + t1 * sn);
}

// ---------------- causal flash attention: 4 waves x 32 q-rows, swapped-QK 32x32 ----------------
// Double-buffered K/V LDS; one barrier per tile; QK split into 4 independent MFMA chains.
__global__ __launch_bounds__(256, 2) void attn_kernel(
    const short* __restrict__ Q, const short* __restrict__ Kg,
    const short* __restrict__ Vt, short* __restrict__ ctx) {
    __shared__ short Ksm[2][64 * 192];    // 2 x 24KB, swizzled linear
    __shared__ short Vsm[2][128 * 64];    // 2 x 16KB, V^T (d,k), swizzled
    int tid = threadIdx.x, lane = tid & 63, w = tid >> 6;
    int hf = lane >> 5, l31 = lane & 31;
    // complementary-pair mapping (blocks c and c+256 share a CU)
    int bid = blockIdx.x;
    int half = bid >> 8, a = (bid & 255) >> 5;
    int qt = half ? a : 15 - a;
    int bh = bid & 31;
    int bb = bh >> 4, hd = bh & 15;
    int q0 = qt * 128;
    const short* Qp = Q + (size_t)bh * SS * DQK;
    const short* Kp = Kg + (size_t)bh * SS * DQK;
    const char*  Vp = (const char*)(Vt + (size_t)bh * HDD * SS);
    int wr0 = q0 + w * 32;
    int qrow = wr0 + l31;               // this lane's softmax row
    const float scale = 0.07216878364870323f;   // 1/sqrt(192)
    const float L2E = 1.44269504088896f;

    // Q as B-operand fragments: B[k=8*hf+j][col=l31], dims 16s+8hf+j
    bf16x8 qf[12];
#pragma unroll
    for (int s = 0; s < 12; s++)
        qf[s] = *(const bf16x8*)(Qp + (size_t)qrow * DQK + s * 16 + hf * 8);

    f32x16 acc[4] = {};   // O: acc[n] rows=(r&3)+8*(r>>2)+4*hf, d=n*32+l31
    float mrow = -1e30f, lsum = 0.f;
    int nt = 2 * qt + 2;

    auto stageK = [&](int key0, int b) {
#pragma unroll
        for (int pp = 0; pp < 6; pp++) {
            int flat = pp * 4096 + tid * 16;          // byte offset in 64x384B tile
            int row = flat / 384, bir = flat - row * 384;
            const char* src = (const char*)Kp + (size_t)(key0 + row) * 384 + (bir ^ ((row & 7) << 4));
            GLOAD16(src, (char*)Ksm[b] + flat);
        }
    };
    auto stageV = [&](int key0, int b) {
#pragma unroll
        for (int c = 0; c < 4; c++) {
            int flat = c * 4096 + tid * 16;           // byte offset in 128x128B tile
            int d = flat >> 7, bik = flat & 127;
            const char* src = Vp + (size_t)d * (SS * 2) + (size_t)key0 * 2 + (bik ^ ((d & 7) << 4));
            GLOAD16(src, (char*)Vsm[b] + flat);
        }
    };

    stageK(0, 0); stageV(0, 0);
    __syncthreads();   // tile 0 ready

    for (int t0 = 0; t0 < nt; t0++) {
        int key0 = t0 * 64;
        int cur = t0 & 1;
        if (t0 + 1 < nt) { stageK(key0 + 64, cur ^ 1); stageV(key0 + 64, cur ^ 1); }
        bool active = (key0 <= wr0 + 31);
        if (active) {
            // ---- swapped QK^T: D[key][qrow], 4 independent MFMA chains ----
            f32x16 z = {};
            f32x16 s0a = z, s0b = z, s1a = z, s1b = z;
            int xr = (l31 & 7) << 4;
            const char* Kb = (const char*)Ksm[cur];
            __builtin_amdgcn_s_setprio(1);
#pragma unroll
            for (int s = 0; s < 12; s += 2) {
                bf16x8 k0 = *(const bf16x8*)(Kb + l31 * 384 + ((s * 32 + hf * 16) ^ xr));
                bf16x8 k1 = *(const bf16x8*)(Kb + (32 + l31) * 384 + ((s * 32 + hf * 16) ^ xr));
                s0a = __builtin_amdgcn_mfma_f32_32x32x16_bf16(k0, qf[s], s0a, 0, 0, 0);
                s1a = __builtin_amdgcn_mfma_f32_32x32x16_bf16(k1, qf[s], s1a, 0, 0, 0);
                bf16x8 k0b = *(const bf16x8*)(Kb + l31 * 384 + (((s + 1) * 32 + hf * 16) ^ xr));
                bf16x8 k1b = *(const bf16x8*)(Kb + (32 + l31) * 384 + (((s + 1) * 32 + hf * 16) ^ xr));
                s0b = __builtin_amdgcn_mfma_f32_32x32x16_bf16(k0b, qf[s + 1], s0b, 0, 0, 0);
                s1b = __builtin_amdgcn_mfma_f32_32x32x16_bf16(k1b, qf[s + 1], s1b, 0, 0, 0);
            }
            __builtin_amdgcn_s_setprio(0);
            f32x16 sv0 = s0a + s0b, sv1 = s1a + s1b;
            // ---- mask (raw scores; scale folded into exp) ----
            bool domask = (key0 + 63 > wr0);
            float p[32];
#pragma unroll
            for (int t = 0; t < 2; t++)
#pragma unroll
                for (int r = 0; r < 16; r++) {
                    float v = (t ? sv1[r] : sv0[r]);
                    int key = key0 + 32 * t + (r & 3) + 8 * (r >> 2) + 4 * hf;
                    if (domask && key > qrow) v = -1e30f;
                    p[t * 16 + r] = v;
                }
            // ---- tree max (5-deep instead of 31-deep serial chain) ----
            float tm[16];
#pragma unroll
            for (int i = 0; i < 16; i++) tm[i] = fmaxf(p[i], p[i + 16]);
#pragma unroll
            for (int i = 0; i < 8; i++) tm[i] = fmaxf(tm[i], tm[i + 8]);
#pragma unroll
            for (int i = 0; i < 4; i++) tm[i] = fmaxf(tm[i], tm[i + 4]);
            float pmaxs = fmaxf(fmaxf(tm[0], tm[1]), fmaxf(tm[2], tm[3])) * scale;
            // ---- defer-max rescale (common max computed only when needed) ----
            if (__any(pmaxs > mrow + 8.f)) {
                float pc = fmaxf(pmaxs, __shfl_xor(pmaxs, 32, 64));
                float mn = fmaxf(mrow, pc);
                float al = exp2f((mrow - mn) * L2E);
                mrow = mn;
                lsum *= al;
                float arl[16];
#pragma unroll
                for (int r = 0; r < 16; r++)
                    arl[r] = __shfl(al, (r & 3) + 8 * (r >> 2) + 4 * hf, 64);
#pragma unroll
                for (int n = 0; n < 4; n++)
#pragma unroll
                    for (int r = 0; r < 16; r++)
                        acc[n][r] *= arl[r];
            }
            // ---- exp with folded scale: exp2(p*scale*L2E - mrow*L2E) ----
            float sL = scale * L2E, mL = mrow * L2E;
#pragma unroll
            for (int i = 0; i < 32; i++)
                p[i] = exp2f(fmaf(p[i], sL, -mL));
            // ---- tree sum ----
            float ts[16];
#pragma unroll
            for (int i = 0; i < 16; i++) ts[i] = p[i] + p[i + 16];
#pragma unroll
            for (int i = 0; i < 8; i++) ts[i] = ts[i] + ts[i + 8];
#pragma unroll
            for (int i = 0; i < 4; i++) ts[i] = ts[i] + ts[i + 4];
            lsum += (ts[0] + ts[1]) + (ts[2] + ts[3]);
            // ---- pack P to bf16 + exchange halves for ALL slices first ----
            bf16x8 afv[4];
#pragma unroll
            for (int g = 0; g < 4; g++) {   // slice g: keys key0+16g..+15
                int base = (g >> 1) * 16 + (g & 1) * 8;
                unsigned a01 = cvtpk(p[base + 0], p[base + 1]);
                unsigned a23 = cvtpk(p[base + 2], p[base + 3]);
                unsigned b01 = cvtpk(p[base + 4], p[base + 5]);
                unsigned b23 = cvtpk(p[base + 6], p[base + 7]);
                unsigned s0 = hf ? a01 : b01, s1 = hf ? a23 : b23;
                unsigned r0 = (unsigned)__shfl_xor((int)s0, 32, 64);
                unsigned r1 = (unsigned)__shfl_xor((int)s1, 32, 64);
                union { unsigned u[4]; bf16x8 v; } af;
                af.u[0] = hf ? r0 : a01;
                af.u[1] = hf ? r1 : a23;
                af.u[2] = hf ? b01 : r0;
                af.u[3] = hf ? b23 : r1;
                afv[g] = af.v;
            }
            // ---- PV ----
            const char* Vb = (const char*)Vsm[cur];
            __builtin_amdgcn_s_setprio(1);
#pragma unroll
            for (int g = 0; g < 4; g++)
#pragma unroll
                for (int n = 0; n < 4; n++) {
                    int d = n * 32 + l31;
                    bf16x8 vf = *(const bf16x8*)(Vb + d * 128 + ((g * 32 + hf * 16) ^ ((d & 7) << 4)));
                    acc[n] = __builtin_amdgcn_mfma_f32_32x32x16_bf16(afv[g], vf, acc[n], 0, 0, 0);
                }
            __builtin_amdgcn_s_setprio(0);
        }
        // one barrier per tile: syncs all waves' reads of buf[cur] and drains
        // this tile's prefetch (issued a full tile ago -> no stall)
        __syncthreads();
    }
    // ---- epilogue ----
    lsum += __shfl_xor(lsum, 32, 64);
    float rc = 1.0f / lsum;
    float rcl[16];
#pragma unroll
    for (int r = 0; r < 16; r++)
        rcl[r] = __shfl(rc, (r & 3) + 8 * (r >> 2) + 4 * hf, 64);
#pragma unroll
    for (int n = 0; n < 4; n++)
#pragma unroll
        for (int r = 0; r < 16; r++) {
            int row = wr0 + (r & 3) + 8 * (r >> 2) + 4 * hf;
            int d = n * 32 + l31;
            ctx[((size_t)(bb * SS + row)) * (NHH * HDD) + hd * HDD + d] = f2b(acc[n][r] * rcl[r]);
        }
}

extern "C" void kernel_launch(void* const* d_in, const int* in_sizes, int n_in,
                              void* d_out, int out_size, void* d_ws, size_t ws_size,
                              hipStream_t stream) {
    const float* x     = (const float*)d_in[0];
    const float* W_kvd = (const float*)d_in[1];  const float* b_kvd = (const float*)d_in[2];
    const float* W_ku  = (const float*)d_in[3];  const float* b_ku  = (const float*)d_in[4];
    const float* W_vu  = (const float*)d_in[5];  const float* b_vu  = (const float*)d_in[6];
    const float* W_kr  = (const float*)d_in[7];  const float* b_kr  = (const float*)d_in[8];
    const float* W_qd  = (const float*)d_in[9];  const float* b_qd  = (const float*)d_in[10];
    const float* W_qu  = (const float*)d_in[11]; const float* b_qu  = (const float*)d_in[12];
    const float* W_qr  = (const float*)d_in[13]; const float* b_qr  = (const float*)d_in[14];
    const float* W_o   = (const float*)d_in[15]; const float* b_o   = (const float*)d_in[16];
    float* out = (float*)d_out;

    char* p = (char*)d_ws;
    auto alloc = [&](size_t elems) {
        short* r = (short*)p;
        p += ((elems * 2) + 255) & ~(size_t)255;
        return r;
    };
    short* xb   = alloc((size_t)MROWS * HIDD);
    short* kvc  = alloc((size_t)MROWS * KVCC);
    short* qc   = alloc((size_t)MROWS * QCC);
    short* kbuf = alloc((size_t)BB * NHH * SS * DQK);
    short* qbuf = alloc((size_t)BB * NHH * SS * DQK);
    short* vtb  = alloc((size_t)BB * NHH * HDD * SS);
    short* ctx  = alloc((size_t)MROWS * NHH * HDD);
    short* Wt1  = alloc((size_t)2048 * 2048);
    short* Wt2  = alloc((size_t)5120 * 512);
    short* Wt3  = alloc((size_t)3072 * 1536);
    short* Wt4  = alloc((size_t)2048 * 2048);

    cvt_kernel<<<dim3((MROWS * HIDD) / 1024), dim3(256), 0, stream>>>(x, xb);
    dim3 tb(32, 8);
    wtrans_kernel<<<dim3(15360), tb, 0, stream>>>(
        W_kvd, W_qd, W_ku, W_vu, W_kr, W_qu, W_qr, W_o, Wt1, Wt2, Wt3, Wt4);

    gemm128<1><<<dim3(512), 256, 0, stream>>>(
        xb, Wt1, b_kvd, b_qd, nullptr, kvc, qc, MROWS, 2048, 2048);
    gemm128<2><<<dim3(1280), 256, 0, stream>>>(
        kvc, Wt2, b_ku, b_vu, b_kr, kbuf, vtb, MROWS, 5120, 512);
    gemm128<3><<<dim3(768), 256, 0, stream>>>(
        qc, Wt3, b_qu, b_qr, nullptr, qbuf, nullptr, MROWS, 3072, 1536);

    rope_kernel<<<dim3((2 * BB * NHH * SS * 32) / 256), dim3(256), 0, stream>>>(kbuf, qbuf);

    attn_kernel<<<dim3(512), 256, 0, stream>>>(qbuf, kbuf, vtb, ctx);

    gemm128<0><<<dim3(512), 256, 0, stream>>>(
        ctx, Wt4, b_o, nullptr, nullptr, out, nullptr, MROWS, HIDD, NHH * HDD);
}

// Round 19
// 358.892 us; speedup vs baseline: 1.0872x; 1.0696x over previous
//
#include <hip/hip_runtime.h>
#include <math.h>

#define BB   2
#define SS   2048
#define HIDD 2048
#define NHH  16
#define HDD  128
#define RDD  64
#define KVCC 512
#define QCC  1536
#define DQK  192
#define MROWS 4096

using bf16x8 = __attribute__((ext_vector_type(8))) short;
using short4v = __attribute__((ext_vector_type(4))) short;
using f32x4  = __attribute__((ext_vector_type(4))) float;
using f32x16 = __attribute__((ext_vector_type(16))) float;

static __device__ __forceinline__ float b2f(short s) {
    unsigned u = ((unsigned)(unsigned short)s) << 16;
    union { unsigned u; float f; } v; v.u = u; return v.f;
}
static __device__ __forceinline__ short f2b(float f) {
    union { float f; unsigned u; } v; v.f = f;
    unsigned r = (v.u + 0x7fffu + ((v.u >> 16) & 1u)) >> 16;
    return (short)r;
}
static __device__ __forceinline__ unsigned cvtpk(float lo, float hi) {
    unsigned r;
    asm("v_cvt_pk_bf16_f32 %0, %1, %2" : "=v"(r) : "v"(lo), "v"(hi));
    return r;
}

#define GLOAD16(gsrc, ldst) \
    __builtin_amdgcn_global_load_lds((const __attribute__((address_space(1))) void*)(gsrc), \
                                     (__attribute__((address_space(3))) void*)(ldst), 16, 0, 0)

// ---- wtrans + x-cvt + rope trig table, ONE launch ----
// bid <  15360 : 8 weight transposes (fp32 KxN -> bf16 NxK)
// bid < 17408 : x fp32 -> bf16 (4096 elems/block)
// bid < 17664 : rope table  tab[s*32+i] = (cos, sin)(s * 10000^(-i/32))
__global__ void prep_kernel(
    const float* __restrict__ W0, const float* __restrict__ W1,
    const float* __restrict__ W2, const float* __restrict__ W3,
    const float* __restrict__ W4, const float* __restrict__ W5,
    const float* __restrict__ W6, const float* __restrict__ W7,
    short* __restrict__ D0, short* __restrict__ D1,
    short* __restrict__ D2, short* __restrict__ D3,
    const float* __restrict__ x, short* __restrict__ xb,
    float2* __restrict__ tab) {
    __shared__ float t[32][33];
    int bid = blockIdx.x;
    int tx = threadIdx.x, ty = threadIdx.y;   // block(32,8)
    if (bid >= 17408) {                       // trig table
        int entry = (bid - 17408) * 256 + ty * 32 + tx;
        int s = entry >> 5, i = entry & 31;
        float inv = exp2f(-(float)i * 0.41524101186092034f);
        float sn, cs;
        sincosf((float)s * inv, &sn, &cs);
        tab[entry] = make_float2(cs, sn);
        return;
    }
    if (bid >= 15360) {                       // x convert
        int base = (bid - 15360) * 4096 + (ty * 32 + tx) * 16;
#pragma unroll
        for (int c = 0; c < 4; c++) {
            float4 v = *(const float4*)(x + base + c * 4);
            short4v o;
            o[0] = f2b(v.x); o[1] = f2b(v.y); o[2] = f2b(v.z); o[3] = f2b(v.w);
            *(short4v*)(xb + base + c * 4) = o;
        }
        return;
    }
    const float* W; short* Dst; int K, N, lt;
    if (bid < 4096) {
        if (bid < 1024) { W = W0; Dst = D0;                        K = 2048; N = 512;  lt = bid; }
        else            { W = W1; Dst = D0 + (size_t)512 * 2048;   K = 2048; N = 1536; lt = bid - 1024; }
    } else if (bid < 6656) {
        if (bid < 5120)      { W = W2; Dst = D1;                       K = 512; N = 2048; lt = bid - 4096; }
        else if (bid < 6144) { W = W3; Dst = D1 + (size_t)2048 * 512;  K = 512; N = 2048; lt = bid - 5120; }
        else                 { W = W4; Dst = D1 + (size_t)4096 * 512;  K = 512; N = 1024; lt = bid - 6144; }
    } else if (bid < 11264) {
        if (bid < 9728) { W = W5; Dst = D2;                        K = 1536; N = 2048; lt = bid - 6656; }
        else            { W = W6; Dst = D2 + (size_t)2048 * 1536;  K = 1536; N = 1024; lt = bid - 9728; }
    } else { W = W7; Dst = D3; K = 2048; N = 2048; lt = bid - 11264; }
    int ntx = N >> 5;
    int n0 = (lt % ntx) * 32, k0 = (lt / ntx) * 32;
#pragma unroll
    for (int i = 0; i < 4; i++)
        t[ty + i * 8][tx] = W[(size_t)(k0 + ty + i * 8) * N + n0 + tx];
    __syncthreads();
#pragma unroll
    for (int i = 0; i < 4; i++)
        Dst[(size_t)(n0 + ty + i * 8) * K + k0 + tx] = f2b(t[tx][ty + i * 8]);
}

// ---------------- 128x128 MFMA GEMM, 3-buffer counted-vmcnt + XCD swizzle ----------
// ID 0: fp32 out (+b0).  ID 1: [kvc|qc] bf16.
// ID 2: [ku->kbuf | vu->vtb TRANSPOSED (bh,d,s) | kr->kbuf ROPED].
// ID 3: [qu->qbuf | qr->qbuf ROPED].
template <int ID>
__global__ __launch_bounds__(256) void gemm128(
    const short* __restrict__ A, const short* __restrict__ Bt,
    const float* __restrict__ b0, const float* __restrict__ b1, const float* __restrict__ b2,
    void* __restrict__ C0, void* __restrict__ C1,
    const float2* __restrict__ tab,
    int M, int N, int K) {
    __shared__ short Asm[3][4096];   // 3 x [128][32]
    __shared__ short Bsm[3][4096];
    int tid = threadIdx.x, lane = tid & 63, w = tid >> 6;
    int wm = w >> 1, wn = w & 1;
    // XCD-aware swizzle (grid % 8 == 0): each XCD gets a contiguous chunk
    int nbx = N >> 7;
    int cpx = gridDim.x >> 3;
    int swz = ((int)blockIdx.x & 7) * cpx + ((int)blockIdx.x >> 3);
    int m0 = (swz / nbx) * 128, n0 = (swz % nbx) * 128;
    int fr = lane & 15, fk = (lane >> 4) * 8;
    const short* Ag = A + (size_t)(m0 + (tid >> 2)) * K + (tid & 3) * 8;
    const short* Bg = Bt + (size_t)(n0 + (tid >> 2)) * K + (tid & 3) * 8;
    auto stage = [&](int t, int b) {
        int k0 = t * 32;
        GLOAD16(Ag + k0, &Asm[b][tid * 8]);
        GLOAD16(Ag + k0 + (size_t)64 * K, &Asm[b][2048 + tid * 8]);
        GLOAD16(Bg + k0, &Bsm[b][tid * 8]);
        GLOAD16(Bg + k0 + (size_t)64 * K, &Bsm[b][2048 + tid * 8]);
    };
    f32x4 acc[4][4] = {};
    int NT = K >> 5;
    stage(0, 0);
    stage(1, 1);
    for (int t = 0; t < NT; t++) {
        int cur = t % 3;
        if (t + 1 < NT) asm volatile("s_waitcnt vmcnt(4)" ::: "memory");
        else            asm volatile("s_waitcnt vmcnt(0)" ::: "memory");
        __builtin_amdgcn_s_barrier();
        bf16x8 af[4], bfv[4];
#pragma unroll
        for (int m = 0; m < 4; m++)
            af[m] = *(const bf16x8*)&Asm[cur][(wm * 64 + m * 16 + fr) * 32 + fk];
#pragma unroll
        for (int n = 0; n < 4; n++)
            bfv[n] = *(const bf16x8*)&Bsm[cur][(wn * 64 + n * 16 + fr) * 32 + fk];
#pragma unroll
        for (int m = 0; m < 4; m++)
#pragma unroll
            for (int n = 0; n < 4; n++)
                acc[m][n] = __builtin_amdgcn_mfma_f32_16x16x32_bf16(af[m], bfv[n], acc[m][n], 0, 0, 0);
        __builtin_amdgcn_s_barrier();
        if (t + 2 < NT) stage(t + 2, (t + 2) % 3);
    }
    // ---- fused RoPE path: kr (ID==2, n0>=4096) / qr (ID==3, n0>=2048) tiles ----
    bool ropeTile = (ID == 2 && n0 >= 4096) || (ID == 3 && n0 >= 2048);
    if (ropeTile) {
        int cbase = n0 - (ID == 2 ? 4096 : 2048) + wn * 64;   // 64-aligned head segment
        int h = cbase >> 6;
        const float* bias = (ID == 2) ? b2 : b1;
        short* Dst = (short*)C0;   // kbuf / qbuf
#pragma unroll
        for (int m = 0; m < 4; m++)
#pragma unroll
            for (int r = 0; r < 4; r++) {
                int row = m0 + wm * 64 + m * 16 + ((lane >> 4) << 2) + r;
                int b = row >> 11, s = row & (SS - 1);
                short* o = Dst + (((size_t)(b * NHH + h)) * SS + s) * DQK + HDD + (cbase & 63);
#pragma unroll
                for (int pp = 0; pp < 2; pp++) {
                    int i = pp * 16 + fr;
                    float2 cs = tab[s * 32 + i];
                    float vlo = acc[m][pp][r] + bias[cbase + pp * 16 + fr];
                    float vhi = acc[m][pp + 2][r] + bias[cbase + pp * 16 + 32 + fr];
                    o[i] = f2b(vlo * cs.x - vhi * cs.y);
                    o[i + 32] = f2b(vhi * cs.x + vlo * cs.y);
                }
            }
        return;
    }
#pragma unroll
    for (int m = 0; m < 4; m++)
#pragma unroll
        for (int n = 0; n < 4; n++)
#pragma unroll
            for (int r = 0; r < 4; r++) {
                int row = m0 + wm * 64 + m * 16 + ((lane >> 4) << 2) + r;
                int col = n0 + wn * 64 + n * 16 + fr;
                float v = acc[m][n][r];
                if constexpr (ID == 0) {
                    ((float*)C0)[(size_t)row * N + col] = v + b0[col];
                } else if constexpr (ID == 1) {
                    if (col < KVCC)
                        ((short*)C0)[(size_t)row * KVCC + col] = f2b(v + b0[col]);
                    else
                        ((short*)C1)[(size_t)row * QCC + (col - KVCC)] = f2b(v + b1[col - KVCC]);
                } else if constexpr (ID == 2) {
                    int b = row >> 11, s = row & (SS - 1);
                    if (col < 2048) {
                        int h = col >> 7, d = col & 127;
                        ((short*)C0)[(((size_t)(b * NHH + h)) * SS + s) * DQK + d] = f2b(v + b0[col]);
                    } else {
                        int c = col - 2048; int h = c >> 7, d = c & 127;
                        // direct transposed (bh, d, s) for attention V
                        ((short*)C1)[(((size_t)(b * NHH + h)) * HDD + d) * SS + s] = f2b(v + b1[c]);
                    }
                } else {
                    int b = row >> 11, s = row & (SS - 1);
                    int h = col >> 7, d = col & 127;
                    ((short*)C0)[(((size_t)(b * NHH + h)) * SS + s) * DQK + d] = f2b(v + b0[col]);
                }
            }
}

// ---------------- causal flash attention: 4 waves x 32 q-rows, swapped-QK 32x32 ----------------
// Double-buffered K/V LDS; one barrier per tile; QK split into 4 independent MFMA chains.
__global__ __launch_bounds__(256, 2) void attn_kernel(
    const short* __restrict__ Q, const short* __restrict__ Kg,
    const short* __restrict__ Vt, short* __restrict__ ctx) {
    __shared__ short Ksm[2][64 * 192];    // 2 x 24KB, swizzled linear
    __shared__ short Vsm[2][128 * 64];    // 2 x 16KB, V^T (d,k), swizzled
    int tid = threadIdx.x, lane = tid & 63, w = tid >> 6;
    int hf = lane >> 5, l31 = lane & 31;
    // complementary-pair mapping (blocks c and c+256 share a CU)
    int bid = blockIdx.x;
    int half = bid >> 8, a = (bid & 255) >> 5;
    int qt = half ? a : 15 - a;
    int bh = bid & 31;
    int bb = bh >> 4, hd = bh & 15;
    int q0 = qt * 128;
    const short* Qp = Q + (size_t)bh * SS * DQK;
    const short* Kp = Kg + (size_t)bh * SS * DQK;
    const char*  Vp = (const char*)(Vt + (size_t)bh * HDD * SS);
    int wr0 = q0 + w * 32;
    int qrow = wr0 + l31;               // this lane's softmax row
    const float scale = 0.07216878364870323f;   // 1/sqrt(192)
    const float L2E = 1.44269504088896f;

    // Q as B-operand fragments: B[k=8*hf+j][col=l31], dims 16s+8hf+j
    bf16x8 qf[12];
#pragma unroll
    for (int s = 0; s < 12; s++)
        qf[s] = *(const bf16x8*)(Qp + (size_t)qrow * DQK + s * 16 + hf * 8);

    f32x16 acc[4] = {};   // O: acc[n] rows=(r&3)+8*(r>>2)+4*hf, d=n*32+l31
    float mrow = -1e30f, lsum = 0.f;
    int nt = 2 * qt + 2;

    auto stageK = [&](int key0, int b) {
#pragma unroll
        for (int pp = 0; pp < 6; pp++) {
            int flat = pp * 4096 + tid * 16;          // byte offset in 64x384B tile
            int row = flat / 384, bir = flat - row * 384;
            const char* src = (const char*)Kp + (size_t)(key0 + row) * 384 + (bir ^ ((row & 7) << 4));
            GLOAD16(src, (char*)Ksm[b] + flat);
        }
    };
    auto stageV = [&](int key0, int b) {
#pragma unroll
        for (int c = 0; c < 4; c++) {
            int flat = c * 4096 + tid * 16;           // byte offset in 128x128B tile
            int d = flat >> 7, bik = flat & 127;
            const char* src = Vp + (size_t)d * (SS * 2) + (size_t)key0 * 2 + (bik ^ ((d & 7) << 4));
            GLOAD16(src, (char*)Vsm[b] + flat);
        }
    };

    stageK(0, 0); stageV(0, 0);
    __syncthreads();   // tile 0 ready

    for (int t0 = 0; t0 < nt; t0++) {
        int key0 = t0 * 64;
        int cur = t0 & 1;
        if (t0 + 1 < nt) { stageK(key0 + 64, cur ^ 1); stageV(key0 + 64, cur ^ 1); }
        bool active = (key0 <= wr0 + 31);
        if (active) {
            // ---- swapped QK^T: D[key][qrow], 4 independent MFMA chains ----
            f32x16 z = {};
            f32x16 s0a = z, s0b = z, s1a = z, s1b = z;
            int xr = (l31 & 7) << 4;
            const char* Kb = (const char*)Ksm[cur];
            __builtin_amdgcn_s_setprio(1);
#pragma unroll
            for (int s = 0; s < 12; s += 2) {
                bf16x8 k0 = *(const bf16x8*)(Kb + l31 * 384 + ((s * 32 + hf * 16) ^ xr));
                bf16x8 k1 = *(const bf16x8*)(Kb + (32 + l31) * 384 + ((s * 32 + hf * 16) ^ xr));
                s0a = __builtin_amdgcn_mfma_f32_32x32x16_bf16(k0, qf[s], s0a, 0, 0, 0);
                s1a = __builtin_amdgcn_mfma_f32_32x32x16_bf16(k1, qf[s], s1a, 0, 0, 0);
                bf16x8 k0b = *(const bf16x8*)(Kb + l31 * 384 + (((s + 1) * 32 + hf * 16) ^ xr));
                bf16x8 k1b = *(const bf16x8*)(Kb + (32 + l31) * 384 + (((s + 1) * 32 + hf * 16) ^ xr));
                s0b = __builtin_amdgcn_mfma_f32_32x32x16_bf16(k0b, qf[s + 1], s0b, 0, 0, 0);
                s1b = __builtin_amdgcn_mfma_f32_32x32x16_bf16(k1b, qf[s + 1], s1b, 0, 0, 0);
            }
            __builtin_amdgcn_s_setprio(0);
            f32x16 sv0 = s0a + s0b, sv1 = s1a + s1b;
            // ---- mask (raw scores; scale folded into exp) ----
            bool domask = (key0 + 63 > wr0);
            float p[32];
#pragma unroll
            for (int t = 0; t < 2; t++)
#pragma unroll
                for (int r = 0; r < 16; r++) {
                    float v = (t ? sv1[r] : sv0[r]);
                    int key = key0 + 32 * t + (r & 3) + 8 * (r >> 2) + 4 * hf;
                    if (domask && key > qrow) v = -1e30f;
                    p[t * 16 + r] = v;
                }
            // ---- tree max (5-deep instead of 31-deep serial chain) ----
            float tm[16];
#pragma unroll
            for (int i = 0; i < 16; i++) tm[i] = fmaxf(p[i], p[i + 16]);
#pragma unroll
            for (int i = 0; i < 8; i++) tm[i] = fmaxf(tm[i], tm[i + 8]);
#pragma unroll
            for (int i = 0; i < 4; i++) tm[i] = fmaxf(tm[i], tm[i + 4]);
            float pmaxs = fmaxf(fmaxf(tm[0], tm[1]), fmaxf(tm[2], tm[3])) * scale;
            // ---- defer-max rescale (common max computed only when needed) ----
            if (__any(pmaxs > mrow + 8.f)) {
                float pc = fmaxf(pmaxs, __shfl_xor(pmaxs, 32, 64));
                float mn = fmaxf(mrow, pc);
                float al = exp2f((mrow - mn) * L2E);
                mrow = mn;
                lsum *= al;
                float arl[16];
#pragma unroll
                for (int r = 0; r < 16; r++)
                    arl[r] = __shfl(al, (r & 3) + 8 * (r >> 2) + 4 * hf, 64);
#pragma unroll
                for (int n = 0; n < 4; n++)
#pragma unroll
                    for (int r = 0; r < 16; r++)
                        acc[n][r] *= arl[r];
            }
            // ---- exp with folded scale: exp2(p*scale*L2E - mrow*L2E) ----
            float sL = scale * L2E, mL = mrow * L2E;
#pragma unroll
            for (int i = 0; i < 32; i++)
                p[i] = exp2f(fmaf(p[i], sL, -mL));
            // ---- tree sum ----
            float ts[16];
#pragma unroll
            for (int i = 0; i < 16; i++) ts[i] = p[i] + p[i + 16];
#pragma unroll
            for (int i = 0; i < 8; i++) ts[i] = ts[i] + ts[i + 8];
#pragma unroll
            for (int i = 0; i < 4; i++) ts[i] = ts[i] + ts[i + 4];
            lsum += (ts[0] + ts[1]) + (ts[2] + ts[3]);
            // ---- pack P to bf16 + exchange halves for ALL slices first ----
            bf16x8 afv[4];
#pragma unroll
            for (int g = 0; g < 4; g++) {   // slice g: keys key0+16g..+15
                int base = (g >> 1) * 16 + (g & 1) * 8;
                unsigned a01 = cvtpk(p[base + 0], p[base + 1]);
                unsigned a23 = cvtpk(p[base + 2], p[base + 3]);
                unsigned b01 = cvtpk(p[base + 4], p[base + 5]);
                unsigned b23 = cvtpk(p[base + 6], p[base + 7]);
                unsigned s0 = hf ? a01 : b01, s1 = hf ? a23 : b23;
                unsigned r0 = (unsigned)__shfl_xor((int)s0, 32, 64);
                unsigned r1 = (unsigned)__shfl_xor((int)s1, 32, 64);
                union { unsigned u[4]; bf16x8 v; } af;
                af.u[0] = hf ? r0 : a01;
                af.u[1] = hf ? r1 : a23;
                af.u[2] = hf ? b01 : r0;
                af.u[3] = hf ? b23 : r1;
                afv[g] = af.v;
            }
            // ---- PV ----
            const char* Vb = (const char*)Vsm[cur];
            __builtin_amdgcn_s_setprio(1);
#pragma unroll
            for (int g = 0; g < 4; g++)
#pragma unroll
                for (int n = 0; n < 4; n++) {
                    int d = n * 32 + l31;
                    bf16x8 vf = *(const bf16x8*)(Vb + d * 128 + ((g * 32 + hf * 16) ^ ((d & 7) << 4)));
                    acc[n] = __builtin_amdgcn_mfma_f32_32x32x16_bf16(afv[g], vf, acc[n], 0, 0, 0);
                }
            __builtin_amdgcn_s_setprio(0);
        }
        // one barrier per tile: syncs all waves' reads of buf[cur] and drains
        // this tile's prefetch (issued a full tile ago -> no stall)
        __syncthreads();
    }
    // ---- epilogue ----
    lsum += __shfl_xor(lsum, 32, 64);
    float rc = 1.0f / lsum;
    float rcl[16];
#pragma unroll
    for (int r = 0; r < 16; r++)
        rcl[r] = __shfl(rc, (r & 3) + 8 * (r >> 2) + 4 * hf, 64);
#pragma unroll
    for (int n = 0; n < 4; n++)
#pragma unroll
        for (int r = 0; r < 16; r++) {
            int row = wr0 + (r & 3) + 8 * (r >> 2) + 4 * hf;
            int d = n * 32 + l31;
            ctx[((size_t)(bb * SS + row)) * (NHH * HDD) + hd * HDD + d] = f2b(acc[n][r] * rcl[r]);
        }
}

extern "C" void kernel_launch(void* const* d_in, const int* in_sizes, int n_in,
                              void* d_out, int out_size, void* d_ws, size_t ws_size,
                              hipStream_t stream) {
    const float* x     = (const float*)d_in[0];
    const float* W_kvd = (const float*)d_in[1];  const float* b_kvd = (const float*)d_in[2];
    const float* W_ku  = (const float*)d_in[3];  const float* b_ku  = (const float*)d_in[4];
    const float* W_vu  = (const float*)d_in[5];  const float* b_vu  = (const float*)d_in[6];
    const float* W_kr  = (const float*)d_in[7];  const float* b_kr  = (const float*)d_in[8];
    const float* W_qd  = (const float*)d_in[9];  const float* b_qd  = (const float*)d_in[10];
    const float* W_qu  = (const float*)d_in[11]; const float* b_qu  = (const float*)d_in[12];
    const float* W_qr  = (const float*)d_in[13]; const float* b_qr  = (const float*)d_in[14];
    const float* W_o   = (const float*)d_in[15]; const float* b_o   = (const float*)d_in[16];
    float* out = (float*)d_out;

    char* p = (char*)d_ws;
    auto alloc = [&](size_t elems) {
        short* r = (short*)p;
        p += ((elems * 2) + 255) & ~(size_t)255;
        return r;
    };
    short* xb   = alloc((size_t)MROWS * HIDD);
    short* kvc  = alloc((size_t)MROWS * KVCC);
    short* qc   = alloc((size_t)MROWS * QCC);
    short* kbuf = alloc((size_t)BB * NHH * SS * DQK);
    short* qbuf = alloc((size_t)BB * NHH * SS * DQK);
    short* vtb  = alloc((size_t)BB * NHH * HDD * SS);
    short* ctx  = alloc((size_t)MROWS * NHH * HDD);
    short* Wt1  = alloc((size_t)2048 * 2048);
    short* Wt2  = alloc((size_t)5120 * 512);
    short* Wt3  = alloc((size_t)3072 * 1536);
    short* Wt4  = alloc((size_t)2048 * 2048);
    float2* tab = (float2*)alloc((size_t)65536 * 4);   // 512 KB rope table

    dim3 tb(32, 8);
    prep_kernel<<<dim3(17664), tb, 0, stream>>>(
        W_kvd, W_qd, W_ku, W_vu, W_kr, W_qu, W_qr, W_o, Wt1, Wt2, Wt3, Wt4,
        x, xb, tab);

    gemm128<1><<<dim3(512), 256, 0, stream>>>(
        xb, Wt1, b_kvd, b_qd, nullptr, kvc, qc, nullptr, MROWS, 2048, 2048);
    gemm128<2><<<dim3(1280), 256, 0, stream>>>(
        kvc, Wt2, b_ku, b_vu, b_kr, kbuf, vtb, tab, MROWS, 5120, 512);
    gemm128<3><<<dim3(768), 256, 0, stream>>>(
        qc, Wt3, b_qu, b_qr, nullptr, qbuf, nullptr, tab, MROWS, 3072, 1536);

    attn_kernel<<<dim3(512), 256, 0, stream>>>(qbuf, kbuf, vtb, ctx);

    gemm128<0><<<dim3(512), 256, 0, stream>>>(
        ctx, Wt4, b_o, nullptr, nullptr, out, nullptr, nullptr, MROWS, HIDD, NHH * HDD);
}